// Round 1
// baseline (640.871 us; speedup 1.0000x reference)
//
#include <hip/hip_runtime.h>

#define H 1024
#define NB 5
#define TSTRIDE 131072  // T*H = 128*1024, row stride of features; enc[b,k] = features[b*TSTRIDE + k]

#define BM 64
#define BN 64
#define BK 32
#define LDA 68  // BM + 4 pad: keeps float4 alignment (68*4 B = 272, %16==0) and breaks bank stride

__device__ __forceinline__ float sign_val(float h, float g, float pre, float a) {
    float cand = (pre >= 0.0f) ? pre : a * pre;
    float v = h + g * cand;
    if (v == 0.0f) v = 0.1f;
    return (v > 0.0f) ? 1.0f : -1.0f;
}

// One block per output column j: computes gate[n][j] = sigmoid(enc[j]·(h[n]+keys[n]))
// and base[n][j] = h[n]·Uw[j] + keys[n]·Vw[j] for n=0..4.
__global__ __launch_bounds__(256) void prep_kernel(
    const float* __restrict__ features,
    const float* __restrict__ states,
    const float* __restrict__ Uw,
    const float* __restrict__ Vw,
    const float* __restrict__ keys,
    float* __restrict__ gateT,   // [NB][H]
    float* __restrict__ baseT)   // [NB][H]
{
    const int j = blockIdx.x;
    const int tid = threadIdx.x;
    float accg[NB] = {0.f, 0.f, 0.f, 0.f, 0.f};
    float accb[NB] = {0.f, 0.f, 0.f, 0.f, 0.f};
    const float* encRow = features + (size_t)j * TSTRIDE;
    const float* uRow = Uw + (size_t)j * H;
    const float* vRow = Vw + (size_t)j * H;
    for (int k = tid; k < H; k += 256) {
        const float e = encRow[k];
        const float u = uRow[k];
        const float v = vRow[k];
        #pragma unroll
        for (int n = 0; n < NB; ++n) {
            const float hk = states[n * H + k];
            const float ky = keys[n * H + k];
            accg[n] += e * (hk + ky);
            accb[n] += hk * u + ky * v;
        }
    }
    __shared__ float red[2 * NB][4];
    #pragma unroll
    for (int n = 0; n < NB; ++n) {
        float g = accg[n], b = accb[n];
        #pragma unroll
        for (int off = 32; off > 0; off >>= 1) {
            g += __shfl_down(g, (unsigned)off, 64);
            b += __shfl_down(b, (unsigned)off, 64);
        }
        if ((tid & 63) == 0) {
            red[n][tid >> 6] = g;
            red[NB + n][tid >> 6] = b;
        }
    }
    __syncthreads();
    if (tid < 2 * NB) {
        const float s = red[tid][0] + red[tid][1] + red[tid][2] + red[tid][3];
        if (tid < NB) {
            gateT[tid * H + j] = 1.0f / (1.0f + expf(-s));
        } else {
            baseT[(tid - NB) * H + j] = s;
        }
    }
}

// Tiled f32 GEMM E[b,j] = enc[b,:]·Ww[j,:], fused sign epilogue for all NB slices.
// Grid: (H/BN, H/BM); block 256 threads; each thread computes a 4x4 microtile.
__global__ __launch_bounds__(256) void gemm_sign_kernel(
    const float* __restrict__ features,
    const float* __restrict__ Ww,
    const float* __restrict__ states,
    const float* __restrict__ prelu_a,
    const float* __restrict__ gateT,
    const float* __restrict__ baseT,
    float* __restrict__ out)
{
    __shared__ float As[BK][LDA];  // As[k][b]
    __shared__ float Bs[BK][LDA];  // Bs[k][j]
    const int bb = blockIdx.y * BM;
    const int jb = blockIdx.x * BN;
    const int tid = (int)threadIdx.x;
    const int tx = tid & 15;   // j group
    const int ty = tid >> 4;   // b group

    float acc[4][4] = {};

    for (int k0 = 0; k0 < H; k0 += BK) {
        // Stage 64 rows x 32 k of A and B (float4 along k, transposed into LDS)
        #pragma unroll
        for (int l = 0; l < 2; ++l) {
            const int f = tid + l * 256;     // 0..511
            const int row = f >> 3;          // 0..63
            const int kq = (f & 7) << 2;     // 0,4,..,28
            const float4 av = *(const float4*)(features + (size_t)(bb + row) * TSTRIDE + k0 + kq);
            const float4 bv = *(const float4*)(Ww + (size_t)(jb + row) * H + k0 + kq);
            As[kq + 0][row] = av.x; As[kq + 1][row] = av.y;
            As[kq + 2][row] = av.z; As[kq + 3][row] = av.w;
            Bs[kq + 0][row] = bv.x; Bs[kq + 1][row] = bv.y;
            Bs[kq + 2][row] = bv.z; Bs[kq + 3][row] = bv.w;
        }
        __syncthreads();
        #pragma unroll
        for (int kk = 0; kk < BK; ++kk) {
            const float4 a = *(const float4*)&As[kk][ty << 2];
            const float4 b = *(const float4*)&Bs[kk][tx << 2];
            acc[0][0] += a.x * b.x; acc[0][1] += a.x * b.y; acc[0][2] += a.x * b.z; acc[0][3] += a.x * b.w;
            acc[1][0] += a.y * b.x; acc[1][1] += a.y * b.y; acc[1][2] += a.y * b.z; acc[1][3] += a.y * b.w;
            acc[2][0] += a.z * b.x; acc[2][1] += a.z * b.y; acc[2][2] += a.z * b.z; acc[2][3] += a.z * b.w;
            acc[3][0] += a.w * b.x; acc[3][1] += a.w * b.y; acc[3][2] += a.w * b.z; acc[3][3] += a.w * b.w;
        }
        __syncthreads();
    }

    // Epilogue: out[(n*1024 + b)*1024 + j] = sign(h[n,j] + gate[j,n]*prelu(base[n,j]+E[b,j]))
    const int c = jb + (tx << 2);
    const float4 pa = *(const float4*)(prelu_a + c);
    #pragma unroll
    for (int n = 0; n < NB; ++n) {
        const float4 hv = *(const float4*)(states + n * H + c);
        const float4 gv = *(const float4*)(gateT + n * H + c);
        const float4 sv = *(const float4*)(baseT + n * H + c);
        #pragma unroll
        for (int i = 0; i < 4; ++i) {
            float4 o;
            o.x = sign_val(hv.x, gv.x, sv.x + acc[i][0], pa.x);
            o.y = sign_val(hv.y, gv.y, sv.y + acc[i][1], pa.y);
            o.z = sign_val(hv.z, gv.z, sv.z + acc[i][2], pa.z);
            o.w = sign_val(hv.w, gv.w, sv.w + acc[i][3], pa.w);
            const int row = bb + (ty << 2) + i;
            *(float4*)(out + ((size_t)(n * H + row) * H + c)) = o;
        }
    }
}

extern "C" void kernel_launch(void* const* d_in, const int* in_sizes, int n_in,
                              void* d_out, int out_size, void* d_ws, size_t ws_size,
                              hipStream_t stream) {
    const float* features = (const float*)d_in[0];
    const float* states   = (const float*)d_in[1];
    const float* Uw       = (const float*)d_in[2];
    const float* Vw       = (const float*)d_in[3];
    const float* Ww       = (const float*)d_in[4];
    const float* keys     = (const float*)d_in[5];
    const float* prelu_a  = (const float*)d_in[6];
    float* out = (float*)d_out;

    float* gateT = (float*)d_ws;          // NB*H floats
    float* baseT = gateT + NB * H;        // NB*H floats

    prep_kernel<<<H, 256, 0, stream>>>(features, states, Uw, Vw, keys, gateT, baseT);

    dim3 grid(H / BN, H / BM);
    gemm_sign_kernel<<<grid, 256, 0, stream>>>(features, Ww, states, prelu_a,
                                               gateT, baseT, out);
}